// Round 1
// 306.277 us; speedup vs baseline: 1.2313x; 1.2313x over previous
//
#include <hip/hip_runtime.h>
#include <hip/hip_bf16.h>

// a_mean_op: out = where(deg>0, segment_mean(relu(h @ W.T + b)[src], dst), hr)
// R7: kill the CSR-build write amplification. Old fill_kernel scattered 4B
// stores at random dst slots -> 107 MB WRITE_SIZE (16x amp, non-coherent XCD
// L2s can't merge partial lines). Replace global counting sort with a
// two-level bucket sort:
//   K0 bucket hist (LDS-aggregated, dst>>9, 512 nodes/bucket)
//   K2 1-block scan -> bucket bases/cursors (global deg array + 3 scan
//      kernels + 400KB memset all removed)
//   K3 bin: edges -> bucket-contiguous packed (src | ldst<<17), one global
//      atomic per (block,bucket), ~168B contiguous runs (amp ~1.3x)
//   K4 per-bucket LDS counting sort; eidx/rowptr writes confined to a 33KB
//      window owned by one block/one XCD -> full-line writebacks.
// binned[] is staged in d_out (dead before gather writes it).

#define FEAT 128
#define BM 64
#define NPB 512              // nodes per bucket  (dst >> 9); needs N < 2^17

using bf16 = __hip_bfloat16;
typedef __attribute__((ext_vector_type(8))) short short8_;   // 8 x bf16
typedef __attribute__((ext_vector_type(4))) short bhalf4;    // 4 x bf16
typedef __attribute__((ext_vector_type(4))) float floatx4;

__device__ __forceinline__ bhalf4 cvt4(float4 f) {
    bhalf4 s;
    s[0] = __bfloat16_as_short(__float2bfloat16(f.x));
    s[1] = __bfloat16_as_short(__float2bfloat16(f.y));
    s[2] = __bfloat16_as_short(__float2bfloat16(f.z));
    s[3] = __bfloat16_as_short(__float2bfloat16(f.w));
    return s;
}
__device__ __forceinline__ float4 b2f4(bhalf4 s) {
    float4 f;
    f.x = __bfloat162float(__short_as_bfloat16(s[0]));
    f.y = __bfloat162float(__short_as_bfloat16(s[1]));
    f.z = __bfloat162float(__short_as_bfloat16(s[2]));
    f.w = __bfloat162float(__short_as_bfloat16(s[3]));
    return f;
}

// ---------------------------------------------------------------------------
// K0: bucket histogram over dst (LDS-aggregated) + [W fp32->bf16, 4 blocks]
// ---------------------------------------------------------------------------
__launch_bounds__(256)
__global__ void bhist_wcvt_kernel(const int* __restrict__ dst, int* __restrict__ bcnt, int E,
                                  const float* __restrict__ W, bf16* __restrict__ Wb,
                                  int hb, int B) {
    __shared__ int cnt[256];
    int bid = blockIdx.x;
    int t = threadIdx.x;
    if (bid < hb) {
        cnt[t] = 0;
        __syncthreads();
        int base = bid * 8192;
        #pragma unroll
        for (int i = 0; i < 32; ++i) {
            int e = base + i * 256 + t;
            if (e < E) atomicAdd(&cnt[dst[e] >> 9], 1);
        }
        __syncthreads();
        if (t < B && cnt[t]) atomicAdd(&bcnt[t], cnt[t]);
    } else {
        // W: 128*128 = 16384 float4 over 4 blocks
        int base = ((bid - hb) * 256 + t) * 4;
        #pragma unroll
        for (int i = 0; i < 4; ++i) {
            int v = base + i;
            ((bhalf4*)Wb)[v] = cvt4(((const float4*)W)[v]);
        }
    }
}

// ---------------------------------------------------------------------------
// K1: GEMM hr = bf16(relu(h @ Wb^T + b)); h staged fp32->bf16 in-kernel.
// ---------------------------------------------------------------------------
__launch_bounds__(256)
__global__ void gemm_kernel(const float* __restrict__ h, const bf16* __restrict__ Wb,
                            const float* __restrict__ b, bf16* __restrict__ hr, int M) {
    __shared__ bf16 sA[BM][136];
    __shared__ bf16 sW[FEAT][136];

    const int tid  = threadIdx.x;
    const int row0 = blockIdx.x * BM;

    // stage Wb (bf16): 2048 short8_, 8 per thread
    #pragma unroll
    for (int i = 0; i < 8; ++i) {
        int v = i * 256 + tid;
        int r = v >> 4;
        int c = (v & 15) * 8;
        *(short8_*)(&sW[r][c]) = *(const short8_*)(Wb + (size_t)r * FEAT + c);
    }
    // stage A (fp32 -> bf16): 2048 float4, 8 per thread
    #pragma unroll
    for (int i = 0; i < 8; ++i) {
        int v = i * 256 + tid;
        int r = v >> 5;                 // 32 float4 per row
        int c = (v & 31) * 4;
        int row = row0 + r;
        float4 f = make_float4(0.f, 0.f, 0.f, 0.f);
        if (row < M) f = *(const float4*)(h + (size_t)row * FEAT + c);
        *(bhalf4*)(&sA[r][c]) = cvt4(f);
    }
    __syncthreads();

    const int wave = tid >> 6;
    const int lane = tid & 63;
    const int m    = lane & 15;
    const int ko   = (lane >> 4) * 8;

    floatx4 acc[8];
    #pragma unroll
    for (int t = 0; t < 8; ++t) acc[t] = floatx4{0.f, 0.f, 0.f, 0.f};

    #pragma unroll
    for (int k0 = 0; k0 < FEAT; k0 += 32) {
        short8_ afrag = *(const short8_*)(&sA[wave * 16 + m][k0 + ko]);
        #pragma unroll
        for (int nt = 0; nt < 8; ++nt) {
            short8_ bfrag = *(const short8_*)(&sW[nt * 16 + m][k0 + ko]);
            acc[nt] = __builtin_amdgcn_mfma_f32_16x16x32_bf16(afrag, bfrag, acc[nt], 0, 0, 0);
        }
    }

    const int rbase = row0 + wave * 16 + (lane >> 4) * 4;
    #pragma unroll
    for (int nt = 0; nt < 8; ++nt) {
        int col = nt * 16 + m;
        float bias = b[col];
        #pragma unroll
        for (int r = 0; r < 4; ++r) {
            int row = rbase + r;
            if (row < M) {
                float v = fmaxf(acc[nt][r] + bias, 0.0f);
                hr[(size_t)row * FEAT + col] = __float2bfloat16(v);
            }
        }
    }
}

// ---------------------------------------------------------------------------
// K2: exclusive scan of bucket counts (B <= 256) -> bbase[B+1] and cursor[B]
// ---------------------------------------------------------------------------
__launch_bounds__(256)
__global__ void bscan_kernel(const int* __restrict__ bcnt, int* __restrict__ bbase,
                             int* __restrict__ cursor, int B, int E) {
    __shared__ int sd[256];
    int t = threadIdx.x;
    int v = (t < B) ? bcnt[t] : 0;
    sd[t] = v;
    __syncthreads();
    for (int off = 1; off < 256; off <<= 1) {
        int y = (t >= off) ? sd[t - off] : 0;
        __syncthreads();
        sd[t] += y;
        __syncthreads();
    }
    int excl = sd[t] - v;
    if (t < B) { bbase[t] = excl; cursor[t] = excl; }
    if (t == 0) bbase[B] = E;
}

// ---------------------------------------------------------------------------
// K3: bin edges into bucket-contiguous regions of binned[] (in d_out).
// packed = src | (local_dst << 17).  One global atomic per (block, bucket);
// each block's writes to a bucket are a contiguous run (~42 edges avg).
// ---------------------------------------------------------------------------
__launch_bounds__(256)
__global__ void bin_kernel(const int* __restrict__ src, const int* __restrict__ dst,
                           int* __restrict__ cursor, int* __restrict__ binned,
                           int E, int B) {
    __shared__ int cnt[256];
    __shared__ int resv[256];
    __shared__ int cur[256];
    int t = threadIdx.x;
    cnt[t] = 0; cur[t] = 0;
    __syncthreads();
    int base = blockIdx.x * 8192;
    #pragma unroll
    for (int i = 0; i < 32; ++i) {
        int e = base + i * 256 + t;
        if (e < E) atomicAdd(&cnt[dst[e] >> 9], 1);
    }
    __syncthreads();
    if (t < B && cnt[t]) resv[t] = atomicAdd(&cursor[t], cnt[t]);
    __syncthreads();
    #pragma unroll
    for (int i = 0; i < 32; ++i) {
        int e = base + i * 256 + t;
        if (e < E) {
            int d = dst[e];
            int bk = d >> 9;
            int r = atomicAdd(&cur[bk], 1);
            binned[resv[bk] + r] = src[e] | ((d & (NPB - 1)) << 17);
        }
    }
}

// ---------------------------------------------------------------------------
// K4: per-bucket CSR build. One block per bucket: LDS deg, LDS scan, LDS
// cursors; rowptr + eidx writes confined to this bucket's window (~33 KB).
// ---------------------------------------------------------------------------
__launch_bounds__(256)
__global__ void build_kernel(const int* __restrict__ binned, const int* __restrict__ bbase,
                             int* __restrict__ rowptr, int* __restrict__ eidx,
                             int N, int E) {
    __shared__ int sdeg[NPB];   // becomes exclusive offsets after scan
    __shared__ int scur[NPB];
    __shared__ int ssc[256];
    int t = threadIdx.x;
    int bk = blockIdx.x;
    sdeg[t] = 0; sdeg[t + 256] = 0;
    scur[t] = 0; scur[t + 256] = 0;
    __syncthreads();

    int base = bbase[bk];
    int cnt  = bbase[bk + 1] - base;

    // pass 1: local degree count
    for (int i = t; i < cnt; i += 256) {
        int p = binned[base + i];
        atomicAdd(&sdeg[(p >> 17) & (NPB - 1)], 1);
    }
    __syncthreads();

    // scan NPB=512 entries with 256 threads (2 per thread)
    int d0 = sdeg[2 * t];
    int d1 = sdeg[2 * t + 1];
    int s  = d0 + d1;
    ssc[t] = s;
    __syncthreads();
    for (int off = 1; off < 256; off <<= 1) {
        int y = (t >= off) ? ssc[t - off] : 0;
        __syncthreads();
        ssc[t] += y;
        __syncthreads();
    }
    int excl0 = ssc[t] - s;     // exclusive for element 2t

    // rowptr for this bucket's nodes
    int node0 = bk * NPB + 2 * t;
    if (node0 < N)     rowptr[node0]     = base + excl0;
    if (node0 + 1 < N) rowptr[node0 + 1] = base + excl0 + d0;
    if (bk == 0 && t == 0) rowptr[N] = E;

    sdeg[2 * t]     = excl0;
    sdeg[2 * t + 1] = excl0 + d0;
    __syncthreads();

    // pass 2: fill eidx (writes land inside [base, base+cnt) -> L2-resident)
    for (int i = t; i < cnt; i += 256) {
        int p = binned[base + i];
        int ld = (p >> 17) & (NPB - 1);
        int slot = atomicAdd(&scur[ld], 1);
        eidx[base + sdeg[ld] + slot] = p & 0x1FFFF;
    }
}

// ---------------------------------------------------------------------------
// K5: gather. One wave per node; half-wave (32 lanes) per edge, 8B bhalf4
// loads, 4 pair-iters unrolled = 8 edges in flight, shfl_xor(32) combine.
// ---------------------------------------------------------------------------
__launch_bounds__(256)
__global__ void gather_kernel(const bf16* __restrict__ hr,
                              const int* __restrict__ rowptr,
                              const int* __restrict__ eidx,
                              float* __restrict__ out, int N) {
    int node = blockIdx.x * 4 + (threadIdx.x >> 6);
    if (node >= N) return;
    int lane = threadIdx.x & 63;
    int half = lane >> 5;          // which edge of the pair
    int l32  = lane & 31;          // bhalf4 index within a 256B row

    int beg = rowptr[node];
    int end = rowptr[node + 1];

    const bhalf4* hp4 = (const bhalf4*)hr;   // 32 per row
    float4 a0 = make_float4(0.f,0.f,0.f,0.f), a1 = make_float4(0.f,0.f,0.f,0.f);
    float4 a2 = make_float4(0.f,0.f,0.f,0.f), a3 = make_float4(0.f,0.f,0.f,0.f);

    int e = beg;
    for (; e + 7 < end; e += 8) {
        int s0 = eidx[e + 0 + half];
        int s1 = eidx[e + 2 + half];
        int s2 = eidx[e + 4 + half];
        int s3 = eidx[e + 6 + half];
        float4 f0 = b2f4(hp4[(size_t)s0 * 32 + l32]);
        float4 f1 = b2f4(hp4[(size_t)s1 * 32 + l32]);
        float4 f2 = b2f4(hp4[(size_t)s2 * 32 + l32]);
        float4 f3 = b2f4(hp4[(size_t)s3 * 32 + l32]);
        a0.x += f0.x; a0.y += f0.y; a0.z += f0.z; a0.w += f0.w;
        a1.x += f1.x; a1.y += f1.y; a1.z += f1.z; a1.w += f1.w;
        a2.x += f2.x; a2.y += f2.y; a2.z += f2.z; a2.w += f2.w;
        a3.x += f3.x; a3.y += f3.y; a3.z += f3.z; a3.w += f3.w;
    }
    for (; e < end; e += 2) {
        int ei = e + half;
        if (ei < end) {
            int s0 = eidx[ei];
            float4 f0 = b2f4(hp4[(size_t)s0 * 32 + l32]);
            a0.x += f0.x; a0.y += f0.y; a0.z += f0.z; a0.w += f0.w;
        }
    }

    a0.x += a1.x + a2.x + a3.x;
    a0.y += a1.y + a2.y + a3.y;
    a0.z += a1.z + a2.z + a3.z;
    a0.w += a1.w + a2.w + a3.w;
    a0.x += __shfl_xor(a0.x, 32, 64);
    a0.y += __shfl_xor(a0.y, 32, 64);
    a0.z += __shfl_xor(a0.z, 32, 64);
    a0.w += __shfl_xor(a0.w, 32, 64);

    int d = end - beg;
    float4 r;
    if (d > 0) {
        float inv = 1.0f / (float)d;
        r.x = a0.x * inv; r.y = a0.y * inv; r.z = a0.z * inv; r.w = a0.w * inv;
    } else {
        r = b2f4(hp4[(size_t)node * 32 + l32]);
    }
    if (half == 0)
        *(float4*)(out + (size_t)node * FEAT + l32 * 4) = r;
}

// ---------------------------------------------------------------------------
extern "C" void kernel_launch(void* const* d_in, const int* in_sizes, int n_in,
                              void* d_out, int out_size, void* d_ws, size_t ws_size,
                              hipStream_t stream) {
    const float* h   = (const float*)d_in[0];
    const int*   src = (const int*)d_in[2];
    const int*   dst = (const int*)d_in[3];
    const float* W   = (const float*)d_in[4];
    const float* b   = (const float*)d_in[5];
    float* out = (float*)d_out;

    const int N = in_sizes[0] / FEAT;
    const int E = in_sizes[2];
    const int B = (N + NPB - 1) / NPB;          // buckets (<= 256 for N <= 128K)

    // ws: hr bf16[N*128] | Wb bf16[128*128] | rowptr int[N+1]
    //   | eidx int[E] | bcnt int[256] | bbase int[257] | cursor int[256]
    char* ws = (char*)d_ws;
    size_t off = 0;
    bf16* hr     = (bf16*)(ws + off); off += (size_t)N * FEAT * 2;
    bf16* Wb     = (bf16*)(ws + off); off += (size_t)FEAT * FEAT * 2;
    int*  rowptr = (int*)(ws + off);  off += (size_t)(N + 1) * 4;
    int*  eidx   = (int*)(ws + off);  off += (size_t)E * 4;
    int*  bcnt   = (int*)(ws + off);  off += 256 * 4;
    int*  bbase  = (int*)(ws + off);  off += 257 * 4;
    int*  cursor = (int*)(ws + off);  off += 256 * 4;

    // binned edge staging lives in d_out (6.4 MB of 51.2 MB; dead before
    // gather overwrites out).
    int* binned = (int*)d_out;

    (void)hipMemsetAsync(bcnt, 0, 256 * 4, stream);

    const int hb = (E + 8191) / 8192;
    bhist_wcvt_kernel<<<dim3(hb + 4), dim3(256), 0, stream>>>(dst, bcnt, E, W, Wb, hb, B);

    const int gb = (N + BM - 1) / BM;
    gemm_kernel<<<dim3(gb), dim3(256), 0, stream>>>(h, Wb, b, hr, N);

    bscan_kernel<<<dim3(1), dim3(256), 0, stream>>>(bcnt, bbase, cursor, B, E);
    bin_kernel<<<dim3(hb), dim3(256), 0, stream>>>(src, dst, cursor, binned, E, B);
    build_kernel<<<dim3(B), dim3(256), 0, stream>>>(binned, bbase, rowptr, eidx, N, E);
    gather_kernel<<<dim3((N + 3) / 4), dim3(256), 0, stream>>>(hr, rowptr, eidx, out, N);
}